// Round 1
// baseline (1567.954 us; speedup 1.0000x reference)
//
#include <hip/hip_runtime.h>
#include <hip/hip_bf16.h>

// Problem constants (DilatedAttention): B=2, S=8192, D=1024, H=16, hd=64,
// SEGMENT=2048, DILATION=2 -> n_seg=4, L=1024, tokens = B*n_seg*L = 8192.
#define D_MODEL 1024
#define NHEADS  16
#define HD      64
#define TOKENS  8192

// Gathered x row for token t (t in [0,8192)):
//   b = t/4096, seg = (t/1024)%4, l = t%1024
//   xrow = b*8192 + seg*2048 + 2*l = (t>>10)*2048 + (t&1023)*2

// ---------------------------------------------------------------------------
// SGEMM: C[M][N] = A[M][K] * B[K][N] + bias[N]   (fp32, row-major)
// GATHER=true remaps A row indices through the dilation gather (lda == K).
// 128x128 tile, BK=16, 256 threads, 8x8 per-thread micro-tile.
// ---------------------------------------------------------------------------
template<bool GATHER>
__global__ __launch_bounds__(256)
void sgemm_kernel(const float* __restrict__ A, const float* __restrict__ B,
                  const float* __restrict__ bias, float* __restrict__ C,
                  int M, int N, int K)
{
    const int BM = 128, BN = 128, BK = 16;
    __shared__ float As[BK][BM];   // k-major (transposed on store)
    __shared__ float Bs[BK][BN];

    const int tid = threadIdx.x;
    const int tx = tid & 15;       // 0..15 -> output col block
    const int ty = tid >> 4;       // 0..15 -> output row block
    const int row0 = blockIdx.y * BM;
    const int col0 = blockIdx.x * BN;

    float acc[8][8];
#pragma unroll
    for (int i = 0; i < 8; i++)
#pragma unroll
        for (int j = 0; j < 8; j++) acc[i][j] = 0.f;

    for (int k0 = 0; k0 < K; k0 += BK) {
        // ---- load A tile: 128 rows x 16 k = 512 float4, 2 per thread ----
#pragma unroll
        for (int p = 0; p < 2; p++) {
            int f4 = tid + p * 256;        // 0..511
            int r  = f4 >> 2;              // row in tile 0..127
            int kc = (f4 & 3) * 4;         // 0,4,8,12
            int grow = row0 + r;
            long arow;
            if (GATHER) arow = (long)((grow >> 10) * 2048 + (grow & 1023) * 2);
            else        arow = grow;
            float4 v = *reinterpret_cast<const float4*>(&A[arow * (long)K + k0 + kc]);
            As[kc + 0][r] = v.x;
            As[kc + 1][r] = v.y;
            As[kc + 2][r] = v.z;
            As[kc + 3][r] = v.w;
        }
        // ---- load B tile: 16 k x 128 cols = 512 float4, 2 per thread ----
#pragma unroll
        for (int p = 0; p < 2; p++) {
            int f4 = tid + p * 256;        // 0..511
            int kr = f4 >> 5;              // 0..15
            int c4 = (f4 & 31) * 4;        // 0..124
            float4 v = *reinterpret_cast<const float4*>(&B[(long)(k0 + kr) * N + col0 + c4]);
            *reinterpret_cast<float4*>(&Bs[kr][c4]) = v;
        }
        __syncthreads();

#pragma unroll
        for (int kk = 0; kk < BK; kk++) {
            float a[8], b[8];
            *reinterpret_cast<float4*>(&a[0]) = *reinterpret_cast<float4*>(&As[kk][ty * 8]);
            *reinterpret_cast<float4*>(&a[4]) = *reinterpret_cast<float4*>(&As[kk][ty * 8 + 4]);
            *reinterpret_cast<float4*>(&b[0]) = *reinterpret_cast<float4*>(&Bs[kk][tx * 8]);
            *reinterpret_cast<float4*>(&b[4]) = *reinterpret_cast<float4*>(&Bs[kk][tx * 8 + 4]);
#pragma unroll
            for (int i = 0; i < 8; i++)
#pragma unroll
                for (int j = 0; j < 8; j++)
                    acc[i][j] = fmaf(a[i], b[j], acc[i][j]);
        }
        __syncthreads();
    }

    // ---- epilogue: add bias, store ----
#pragma unroll
    for (int i = 0; i < 8; i++) {
        long crow = row0 + ty * 8 + i;
#pragma unroll
        for (int j = 0; j < 8; j += 4) {
            int gc = col0 + tx * 8 + j;
            float4 v;
            v.x = acc[i][j + 0] + bias[gc + 0];
            v.y = acc[i][j + 1] + bias[gc + 1];
            v.z = acc[i][j + 2] + bias[gc + 2];
            v.w = acc[i][j + 3] + bias[gc + 3];
            *reinterpret_cast<float4*>(&C[crow * (long)N + gc]) = v;
        }
    }
}

// ---------------------------------------------------------------------------
// Attention: per (b,seg,h): softmax(Q K^T / 8) V over L=1024 keys, hd=64.
// One thread per q-row. K/V tiles (64 keys x 64 dims) staged in LDS;
// inner loop reads are wave-uniform (broadcast, conflict-free).
// qkv layout: [token][3072] with q at +0, k at +1024, v at +2048, head h
// at offset h*64 within each. ctx layout: [token][1024], head-major.
// ---------------------------------------------------------------------------
__global__ __launch_bounds__(256)
void attn_kernel(const float* __restrict__ qkv, float* __restrict__ ctx)
{
    __shared__ float Ks[64][64];
    __shared__ float Vs[64][64];

    const int bsh  = blockIdx.x;      // 0..127 = (b*4+seg)*16 + h
    const int qt   = blockIdx.y;      // 0..3
    const int bseg = bsh >> 4;        // 0..7
    const int h    = bsh & 15;
    const int tid  = threadIdx.x;
    const int l    = qt * 256 + tid;  // q row 0..1023
    const long tb  = (long)bseg * 1024;

    // load q row into registers
    float q[HD];
    const float* qptr = qkv + (tb + l) * 3072 + h * HD;
#pragma unroll
    for (int c = 0; c < HD; c += 4)
        *reinterpret_cast<float4*>(&q[c]) = *reinterpret_cast<const float4*>(&qptr[c]);

    float m = -1e30f, lsum = 0.f;
    float o[HD];
#pragma unroll
    for (int c = 0; c < HD; c++) o[c] = 0.f;

    for (int t = 0; t < 16; t++) {
        // stage 64 keys + 64 values (each 64x64 fp32 = 1024 float4 total)
#pragma unroll
        for (int p = 0; p < 4; p++) {
            int f4 = tid + p * 256;        // 0..1023
            int j  = f4 >> 4;              // key 0..63
            int c  = (f4 & 15) * 4;        // 0..60
            long base = (tb + t * 64 + j) * 3072 + h * HD + c;
            *reinterpret_cast<float4*>(&Ks[j][c]) =
                *reinterpret_cast<const float4*>(&qkv[base + 1024]);
            *reinterpret_cast<float4*>(&Vs[j][c]) =
                *reinterpret_cast<const float4*>(&qkv[base + 2048]);
        }
        __syncthreads();

        for (int jc = 0; jc < 64; jc += 8) {
            float s[8];
#pragma unroll
            for (int u = 0; u < 8; u++) {
                const float* kr = &Ks[jc + u][0];
                float s0 = 0.f, s1 = 0.f, s2 = 0.f, s3 = 0.f;
#pragma unroll
                for (int c = 0; c < HD; c += 4) {
                    s0 = fmaf(q[c + 0], kr[c + 0], s0);
                    s1 = fmaf(q[c + 1], kr[c + 1], s1);
                    s2 = fmaf(q[c + 2], kr[c + 2], s2);
                    s3 = fmaf(q[c + 3], kr[c + 3], s3);
                }
                s[u] = (s0 + s1 + s2 + s3) * 0.125f;
            }
            float mt = s[0];
#pragma unroll
            for (int u = 1; u < 8; u++) mt = fmaxf(mt, s[u]);
            float mnew = fmaxf(m, mt);
            float corr = __expf(m - mnew);
            float p[8];
            float psum = 0.f;
#pragma unroll
            for (int u = 0; u < 8; u++) { p[u] = __expf(s[u] - mnew); psum += p[u]; }
            lsum = lsum * corr + psum;
#pragma unroll
            for (int c = 0; c < HD; c++) o[c] *= corr;
#pragma unroll
            for (int u = 0; u < 8; u++) {
                const float* vr = &Vs[jc + u][0];
#pragma unroll
                for (int c = 0; c < HD; c++) o[c] = fmaf(p[u], vr[c], o[c]);
            }
            m = mnew;
        }
        __syncthreads();
    }

    const float inv = 1.f / lsum;
    float* optr = ctx + (tb + l) * 1024 + h * HD;
#pragma unroll
    for (int c = 0; c < HD; c += 4) {
        float4 v;
        v.x = o[c + 0] * inv;
        v.y = o[c + 1] * inv;
        v.z = o[c + 2] * inv;
        v.w = o[c + 3] * inv;
        *reinterpret_cast<float4*>(&optr[c]) = v;
    }
}

// ---------------------------------------------------------------------------
extern "C" void kernel_launch(void* const* d_in, const int* in_sizes, int n_in,
                              void* d_out, int out_size, void* d_ws, size_t ws_size,
                              hipStream_t stream)
{
    const float* x    = (const float*)d_in[0];   // (2, 8192, 1024)
    const float* Wqkv = (const float*)d_in[1];   // (1024, 3072)
    const float* bqkv = (const float*)d_in[2];   // (3072,)
    const float* Wout = (const float*)d_in[3];   // (1024, 1024)
    const float* bout = (const float*)d_in[4];   // (1024,)
    float* out = (float*)d_out;                  // (2, 4096, 1024)

    // workspace: qkv (8192x3072 fp32 = 96 MB), ctx (8192x1024 fp32 = 32 MB)
    float* qkv = (float*)d_ws;
    float* ctx = qkv + (size_t)TOKENS * 3072;

    // 1) gather + QKV projection: (8192 x 1024) @ (1024 x 3072) + bqkv
    sgemm_kernel<true><<<dim3(3072 / 128, TOKENS / 128), 256, 0, stream>>>(
        x, Wqkv, bqkv, qkv, TOKENS, 3072, 1024);

    // 2) attention per (b,seg,h), flash-style over 16 key tiles of 64
    attn_kernel<<<dim3(128, 4), 256, 0, stream>>>(qkv, ctx);

    // 3) output projection: (8192 x 1024) @ (1024 x 1024) + bout
    sgemm_kernel<false><<<dim3(1024 / 128, TOKENS / 128), 256, 0, stream>>>(
        ctx, Wout, bout, out, TOKENS, 1024, 1024);
}

// Round 2
// 929.980 us; speedup vs baseline: 1.6860x; 1.6860x over previous
//
#include <hip/hip_runtime.h>
#include <hip/hip_bf16.h>

// DilatedAttention: B=2, S=8192, D=1024, H=16, hd=64, SEGMENT=2048, DILATION=2
// -> n_seg=4, L=1024, tokens = 8192. Gathered x row for token t:
//   xrow = (t>>10)*2048 + (t&1023)*2
#define TOKENS  8192
#define HD      64

typedef short  short8 __attribute__((ext_vector_type(8)));
typedef float  f32x4  __attribute__((ext_vector_type(4)));
typedef unsigned short us4 __attribute__((ext_vector_type(4)));

__device__ __forceinline__ unsigned short f2bf_rne(float f) {
    unsigned u = __float_as_uint(f);
    unsigned r = (u + 0x7FFFu + ((u >> 16) & 1u)) >> 16;
    return (unsigned short)r;
}
__device__ __forceinline__ float bf2f(unsigned short h) {
    return __uint_as_float((unsigned)h << 16);
}
__device__ __forceinline__ void gld16(const void* gptr, void* lptr) {
    __builtin_amdgcn_global_load_lds(
        (const __attribute__((address_space(1))) void*)gptr,
        (__attribute__((address_space(3))) void*)lptr, 16, 0, 0);
}

// ---------------------------------------------------------------------------
// prep_x: gather + fp32 -> bf16 hi/lo split.  Ax[t][k] = hi, Ax[t][1024+k] = lo
// grid: 8192 blocks x 256 threads (4 cols/thread)
// ---------------------------------------------------------------------------
__global__ __launch_bounds__(256)
void prep_x_kernel(const float* __restrict__ x, unsigned short* __restrict__ Ax)
{
    const int t = blockIdx.x;
    const int c = threadIdx.x * 4;
    const long xrow = (long)((t >> 10) * 2048 + (t & 1023) * 2);
    float4 v = *reinterpret_cast<const float4*>(&x[xrow * 1024 + c]);
    float f[4] = {v.x, v.y, v.z, v.w};
    us4 hv, lv;
#pragma unroll
    for (int u = 0; u < 4; u++) {
        unsigned short hi = f2bf_rne(f[u]);
        hv[u] = hi;
        lv[u] = f2bf_rne(f[u] - bf2f(hi));
    }
    *reinterpret_cast<us4*>(&Ax[(size_t)t * 2048 + c]) = hv;
    *reinterpret_cast<us4*>(&Ax[(size_t)t * 2048 + 1024 + c]) = lv;
}

// ---------------------------------------------------------------------------
// prep_w: W[K=1024][N] fp32 -> Wt[N][2048] bf16 (transposed, hi|lo along k)
// grid: (N/32, 1024/32), 256 threads; 32x32 LDS tile transpose
// ---------------------------------------------------------------------------
__global__ __launch_bounds__(256)
void prep_w_kernel(const float* __restrict__ W, unsigned short* __restrict__ Wt, int N)
{
    __shared__ float T[32][33];
    const int n0 = blockIdx.x * 32, k0 = blockIdx.y * 32;
    const int tid = threadIdx.x;
#pragma unroll
    for (int p = 0; p < 4; p++) {
        int r = p * 8 + (tid >> 5), c = tid & 31;
        T[r][c] = W[(long)(k0 + r) * N + n0 + c];
    }
    __syncthreads();
#pragma unroll
    for (int p = 0; p < 4; p++) {
        int on = p * 8 + (tid >> 5), ok = tid & 31;
        float v = T[ok][on];
        unsigned short hi = f2bf_rne(v);
        unsigned short lo = f2bf_rne(v - bf2f(hi));
        Wt[(size_t)(n0 + on) * 2048 + k0 + ok] = hi;
        Wt[(size_t)(n0 + on) * 2048 + 1024 + k0 + ok] = lo;
    }
}

// ---------------------------------------------------------------------------
// bf16x3 MFMA GEMM:  C[8192][N] = A * B + bias  (emulated fp32 via hi/lo)
// A: [8192][2048] bf16 (hi cols 0..1023, lo cols 1024..2047)
// Bt: [N][2048] bf16 (B^T, hi|lo along k)
// 3 K-segments: (Ahi,Bhi), (Alo,Bhi), (Ahi,Blo); 128x128 tile, BK=32,
// 256 thr = 4 waves (2x2), 16x16x32 MFMA, global_load_lds staging (m97).
// ---------------------------------------------------------------------------
__global__ __launch_bounds__(256)
void mfma_gemm_kernel(const unsigned short* __restrict__ A,
                      const unsigned short* __restrict__ Bt,
                      const float* __restrict__ bias,
                      float* __restrict__ C, int N)
{
    __shared__ unsigned short As[128][32];   // 8 KB
    __shared__ unsigned short Bs[128][32];   // 8 KB

    const int tid = threadIdx.x;
    const int l = tid & 63, w = tid >> 6;
    const int wr = w >> 1, wc = w & 1;
    const int trow0 = blockIdx.y * 128;
    const int col0  = blockIdx.x * 128;

    const int srow = l >> 2;        // staging: row within 16-row group
    const int sk   = (l & 3) * 8;   // staging: k element offset (16B chunks)

    f32x4 acc[4][4];
#pragma unroll
    for (int i = 0; i < 4; i++)
#pragma unroll
        for (int j = 0; j < 4; j++) acc[i][j] = (f32x4){0.f, 0.f, 0.f, 0.f};

    for (int ks = 0; ks < 96; ++ks) {
        const int seg = ks >> 5;
        const int k0  = (ks & 31) * 32;
        const int acol = ((seg == 1) ? 1024 : 0) + k0;   // ASEL = {0,1,0}
        const int bcol = ((seg == 2) ? 1024 : 0) + k0;   // BSEL = {0,0,1}

        // ---- stage A,B tiles: 8 x 1KB chunks each, 2 per wave ----
#pragma unroll
        for (int p = 0; p < 2; ++p) {
            const int ia = w * 2 + p;          // 0..7
            const int r  = ia * 16 + srow;
            gld16(&A [(size_t)(trow0 + r) * 2048 + acol + sk], &As[ia * 16][0]);
            gld16(&Bt[(size_t)(col0  + r) * 2048 + bcol + sk], &Bs[ia * 16][0]);
        }
        __syncthreads();   // drains vmcnt -> LDS tiles ready

        // ---- fragments + MFMA ----
        short8 af[4], bfr[4];
#pragma unroll
        for (int i = 0; i < 4; ++i) {
            int r = wr * 64 + i * 16 + (l & 15);
            af[i] = *reinterpret_cast<const short8*>(&As[r][(l >> 4) * 8]);
        }
#pragma unroll
        for (int j = 0; j < 4; ++j) {
            int c = wc * 64 + j * 16 + (l & 15);
            bfr[j] = *reinterpret_cast<const short8*>(&Bs[c][(l >> 4) * 8]);
        }
#pragma unroll
        for (int i = 0; i < 4; ++i)
#pragma unroll
            for (int j = 0; j < 4; ++j)
                acc[i][j] = __builtin_amdgcn_mfma_f32_16x16x32_bf16(
                    af[i], bfr[j], acc[i][j], 0, 0, 0);
        __syncthreads();   // protect LDS from next stage
    }

    // ---- epilogue: bias + fp32 store ----
    // C/D layout (verified m89/m91): col = lane&15, row = (lane>>4)*4 + reg
#pragma unroll
    for (int j = 0; j < 4; ++j) {
        const int gc = col0 + wc * 64 + j * 16 + (l & 15);
        const float bv = bias[gc];
#pragma unroll
        for (int i = 0; i < 4; ++i) {
            const int gr0 = trow0 + wr * 64 + i * 16 + (l >> 4) * 4;
#pragma unroll
            for (int r = 0; r < 4; ++r)
                C[(size_t)(gr0 + r) * N + gc] = acc[i][j][r] + bv;
        }
    }
}

// ---------------------------------------------------------------------------
// Attention (fp32, flash-style): per (b,seg,h), one thread per q-row.
// qkv: [8192][3072] fp32. Writes ctx as bf16 hi/lo: [8192][2048].
// ---------------------------------------------------------------------------
__global__ __launch_bounds__(256)
void attn_kernel(const float* __restrict__ qkv, unsigned short* __restrict__ ctx)
{
    __shared__ float Ks[64][64];
    __shared__ float Vs[64][64];

    const int bsh  = blockIdx.x;      // (b*4+seg)*16 + h
    const int qt   = blockIdx.y;      // 0..3
    const int bseg = bsh >> 4;
    const int h    = bsh & 15;
    const int tid  = threadIdx.x;
    const int lq   = qt * 256 + tid;  // q row 0..1023
    const long tb  = (long)bseg * 1024;

    float q[HD];
    const float* qptr = qkv + (tb + lq) * 3072 + h * HD;
#pragma unroll
    for (int c = 0; c < HD; c += 4)
        *reinterpret_cast<float4*>(&q[c]) = *reinterpret_cast<const float4*>(&qptr[c]);

    float m = -1e30f, lsum = 0.f;
    float o[HD];
#pragma unroll
    for (int c = 0; c < HD; c++) o[c] = 0.f;

    for (int t = 0; t < 16; t++) {
#pragma unroll
        for (int p = 0; p < 4; p++) {
            int f4 = tid + p * 256;
            int j  = f4 >> 4;
            int c  = (f4 & 15) * 4;
            long base = (tb + t * 64 + j) * 3072 + h * HD + c;
            *reinterpret_cast<float4*>(&Ks[j][c]) =
                *reinterpret_cast<const float4*>(&qkv[base + 1024]);
            *reinterpret_cast<float4*>(&Vs[j][c]) =
                *reinterpret_cast<const float4*>(&qkv[base + 2048]);
        }
        __syncthreads();

        for (int jc = 0; jc < 64; jc += 8) {
            float s[8];
#pragma unroll
            for (int u = 0; u < 8; u++) {
                const float* kr = &Ks[jc + u][0];
                float s0 = 0.f, s1 = 0.f, s2 = 0.f, s3 = 0.f;
#pragma unroll
                for (int c = 0; c < HD; c += 4) {
                    s0 = fmaf(q[c + 0], kr[c + 0], s0);
                    s1 = fmaf(q[c + 1], kr[c + 1], s1);
                    s2 = fmaf(q[c + 2], kr[c + 2], s2);
                    s3 = fmaf(q[c + 3], kr[c + 3], s3);
                }
                s[u] = (s0 + s1 + s2 + s3) * 0.125f;
            }
            float mt = s[0];
#pragma unroll
            for (int u = 1; u < 8; u++) mt = fmaxf(mt, s[u]);
            float mnew = fmaxf(m, mt);
            float corr = __expf(m - mnew);
            float p[8];
            float psum = 0.f;
#pragma unroll
            for (int u = 0; u < 8; u++) { p[u] = __expf(s[u] - mnew); psum += p[u]; }
            lsum = lsum * corr + psum;
#pragma unroll
            for (int c = 0; c < HD; c++) o[c] *= corr;
#pragma unroll
            for (int u = 0; u < 8; u++) {
                const float* vr = &Vs[jc + u][0];
#pragma unroll
                for (int c = 0; c < HD; c++) o[c] = fmaf(p[u], vr[c], o[c]);
            }
            m = mnew;
        }
        __syncthreads();
    }

    const float inv = 1.f / lsum;
    unsigned short* optr = ctx + (size_t)(tb + lq) * 2048 + h * HD;
#pragma unroll
    for (int c = 0; c < HD; c += 4) {
        us4 hv, lv;
#pragma unroll
        for (int u = 0; u < 4; u++) {
            float val = o[c + u] * inv;
            unsigned short hi = f2bf_rne(val);
            hv[u] = hi;
            lv[u] = f2bf_rne(val - bf2f(hi));
        }
        *reinterpret_cast<us4*>(&optr[c]) = hv;
        *reinterpret_cast<us4*>(&optr[1024 + c]) = lv;
    }
}

// ---------------------------------------------------------------------------
extern "C" void kernel_launch(void* const* d_in, const int* in_sizes, int n_in,
                              void* d_out, int out_size, void* d_ws, size_t ws_size,
                              hipStream_t stream)
{
    const float* x    = (const float*)d_in[0];   // (2, 8192, 1024)
    const float* Wqkv = (const float*)d_in[1];   // (1024, 3072)
    const float* bqkv = (const float*)d_in[2];   // (3072,)
    const float* Wout = (const float*)d_in[3];   // (1024, 1024)
    const float* bout = (const float*)d_in[4];   // (1024,)
    float* out = (float*)d_out;                  // (2, 4096, 1024)

    // workspace layout (176 MB total)
    char* ws = (char*)d_ws;
    float*          qkv = (float*)ws;                                  // 96 MB
    unsigned short* Ax  = (unsigned short*)(ws + 100663296);           // 32 MB
    unsigned short* Wqt = (unsigned short*)(ws + 100663296 + 33554432);          // 12 MB
    unsigned short* Wot = (unsigned short*)(ws + 100663296 + 33554432 + 12582912);   // 4 MB
    unsigned short* ctx = (unsigned short*)(ws + 100663296 + 33554432 + 12582912 + 4194304); // 32 MB

    // 1) preps: gather+split x; transpose+split weights
    prep_x_kernel<<<TOKENS, 256, 0, stream>>>(x, Ax);
    prep_w_kernel<<<dim3(3072 / 32, 1024 / 32), 256, 0, stream>>>(Wqkv, Wqt, 3072);
    prep_w_kernel<<<dim3(1024 / 32, 1024 / 32), 256, 0, stream>>>(Wout, Wot, 1024);

    // 2) QKV projection (bf16x3 MFMA): [8192][2048]x[3072][2048]^T -> fp32
    mfma_gemm_kernel<<<dim3(3072 / 128, TOKENS / 128), 256, 0, stream>>>(
        Ax, Wqt, bqkv, qkv, 3072);

    // 3) attention, fp32 flash; writes ctx bf16 hi/lo
    attn_kernel<<<dim3(128, 4), 256, 0, stream>>>(qkv, ctx);

    // 4) output projection (bf16x3 MFMA) -> fp32 out
    mfma_gemm_kernel<<<dim3(1024 / 128, TOKENS / 128), 256, 0, stream>>>(
        ctx, Wot, bout, out, 1024);
}

// Round 3
// 388.746 us; speedup vs baseline: 4.0334x; 2.3923x over previous
//
#include <hip/hip_runtime.h>
#include <hip/hip_bf16.h>

// DilatedAttention: B=2, S=8192, D=1024, H=16, hd=64, SEGMENT=2048, DILATION=2
// -> n_seg=4, L=1024, tokens = 8192. Gathered x row for token t:
//   xrow = (t>>10)*2048 + (t&1023)*2
#define TOKENS  8192

typedef short  short8 __attribute__((ext_vector_type(8)));
typedef float  f32x4  __attribute__((ext_vector_type(4)));
typedef float  f32x16 __attribute__((ext_vector_type(16)));
typedef unsigned short us4 __attribute__((ext_vector_type(4)));

__device__ __forceinline__ unsigned short f2bf_rne(float f) {
    unsigned u = __float_as_uint(f);
    unsigned r = (u + 0x7FFFu + ((u >> 16) & 1u)) >> 16;
    return (unsigned short)r;
}
__device__ __forceinline__ float bf2f(unsigned short h) {
    return __uint_as_float((unsigned)h << 16);
}
__device__ __forceinline__ void gld16(const void* gptr, void* lptr) {
    __builtin_amdgcn_global_load_lds(
        (const __attribute__((address_space(1))) void*)gptr,
        (__attribute__((address_space(3))) void*)lptr, 16, 0, 0);
}

// ---------------------------------------------------------------------------
// prep_x: gather + fp32 -> bf16 hi/lo split.  Ax[t][k]=hi, Ax[t][1024+k]=lo
// ---------------------------------------------------------------------------
__global__ __launch_bounds__(256)
void prep_x_kernel(const float* __restrict__ x, unsigned short* __restrict__ Ax)
{
    const int t = blockIdx.x;
    const int c = threadIdx.x * 4;
    const long xrow = (long)((t >> 10) * 2048 + (t & 1023) * 2);
    float4 v = *reinterpret_cast<const float4*>(&x[xrow * 1024 + c]);
    float f[4] = {v.x, v.y, v.z, v.w};
    us4 hv, lv;
#pragma unroll
    for (int u = 0; u < 4; u++) {
        unsigned short hi = f2bf_rne(f[u]);
        hv[u] = hi;
        lv[u] = f2bf_rne(f[u] - bf2f(hi));
    }
    *reinterpret_cast<us4*>(&Ax[(size_t)t * 2048 + c]) = hv;
    *reinterpret_cast<us4*>(&Ax[(size_t)t * 2048 + 1024 + c]) = lv;
}

// ---------------------------------------------------------------------------
// prep_w: W[1024][N] fp32 -> Wt[N][2048] bf16 (transposed, hi|lo along k)
// ---------------------------------------------------------------------------
__global__ __launch_bounds__(256)
void prep_w_kernel(const float* __restrict__ W, unsigned short* __restrict__ Wt, int N)
{
    __shared__ float T[32][33];
    const int n0 = blockIdx.x * 32, k0 = blockIdx.y * 32;
    const int tid = threadIdx.x;
#pragma unroll
    for (int p = 0; p < 4; p++) {
        int r = p * 8 + (tid >> 5), c = tid & 31;
        T[r][c] = W[(long)(k0 + r) * N + n0 + c];
    }
    __syncthreads();
#pragma unroll
    for (int p = 0; p < 4; p++) {
        int on = p * 8 + (tid >> 5), ok = tid & 31;
        float v = T[ok][on];
        unsigned short hi = f2bf_rne(v);
        unsigned short lo = f2bf_rne(v - bf2f(hi));
        Wt[(size_t)(n0 + on) * 2048 + k0 + ok] = hi;
        Wt[(size_t)(n0 + on) * 2048 + 1024 + k0 + ok] = lo;
    }
}

// ---------------------------------------------------------------------------
// bf16x3 MFMA GEMM, 128x128 tile, BK=32, 16x16x32 MFMA (m97 structure).
// EPI=0: C fp32 = A*B + bias.
// EPI=1: QKV epilogue -> writes q/k/v bf16 head-major [bsh][l][64].
// ---------------------------------------------------------------------------
template<int EPI>
__global__ __launch_bounds__(256)
void mfma_gemm_kernel(const unsigned short* __restrict__ A,
                      const unsigned short* __restrict__ Bt,
                      const float* __restrict__ bias,
                      float* __restrict__ C,
                      unsigned short* __restrict__ Qb,
                      unsigned short* __restrict__ Kb,
                      unsigned short* __restrict__ Vb,
                      int N)
{
    __shared__ unsigned short As[128][32];
    __shared__ unsigned short Bs[128][32];

    const int tid = threadIdx.x;
    const int l = tid & 63, w = tid >> 6;
    const int wr = w >> 1, wc = w & 1;
    const int trow0 = blockIdx.y * 128;
    const int col0  = blockIdx.x * 128;

    const int srow = l >> 2;
    const int sk   = (l & 3) * 8;

    f32x4 acc[4][4];
#pragma unroll
    for (int i = 0; i < 4; i++)
#pragma unroll
        for (int j = 0; j < 4; j++) acc[i][j] = (f32x4){0.f, 0.f, 0.f, 0.f};

    for (int ks = 0; ks < 96; ++ks) {
        const int seg = ks >> 5;
        const int k0  = (ks & 31) * 32;
        const int acol = ((seg == 1) ? 1024 : 0) + k0;
        const int bcol = ((seg == 2) ? 1024 : 0) + k0;

#pragma unroll
        for (int p = 0; p < 2; ++p) {
            const int ia = w * 2 + p;
            const int r  = ia * 16 + srow;
            gld16(&A [(size_t)(trow0 + r) * 2048 + acol + sk], &As[ia * 16][0]);
            gld16(&Bt[(size_t)(col0  + r) * 2048 + bcol + sk], &Bs[ia * 16][0]);
        }
        __syncthreads();

        short8 af[4], bfr[4];
#pragma unroll
        for (int i = 0; i < 4; ++i) {
            int r = wr * 64 + i * 16 + (l & 15);
            af[i] = *reinterpret_cast<const short8*>(&As[r][(l >> 4) * 8]);
        }
#pragma unroll
        for (int j = 0; j < 4; ++j) {
            int c = wc * 64 + j * 16 + (l & 15);
            bfr[j] = *reinterpret_cast<const short8*>(&Bs[c][(l >> 4) * 8]);
        }
#pragma unroll
        for (int i = 0; i < 4; ++i)
#pragma unroll
            for (int j = 0; j < 4; ++j)
                acc[i][j] = __builtin_amdgcn_mfma_f32_16x16x32_bf16(
                    af[i], bfr[j], acc[i][j], 0, 0, 0);
        __syncthreads();
    }

#pragma unroll
    for (int j = 0; j < 4; ++j) {
        const int gc = col0 + wc * 64 + j * 16 + (l & 15);
        const float bv = bias[gc];
        if (EPI == 0) {
#pragma unroll
            for (int i = 0; i < 4; ++i) {
                const int gr0 = trow0 + wr * 64 + i * 16 + (l >> 4) * 4;
#pragma unroll
                for (int r = 0; r < 4; ++r)
                    C[(size_t)(gr0 + r) * N + gc] = acc[i][j][r] + bv;
            }
        } else {
            const int which = gc >> 10;
            const int head  = (gc >> 6) & 15;
            const int d     = gc & 63;
            unsigned short* dst = (which == 0) ? Qb : ((which == 1) ? Kb : Vb);
#pragma unroll
            for (int i = 0; i < 4; ++i) {
                const int gr0 = trow0 + wr * 64 + i * 16 + (l >> 4) * 4;
#pragma unroll
                for (int r = 0; r < 4; ++r) {
                    const int gr = gr0 + r;
                    const size_t adr = ((size_t)((gr >> 10) * 16 + head) << 16)
                                     + (size_t)(gr & 1023) * 64 + d;
                    dst[adr] = f2bf_rne(acc[i][j][r] + bv);
                }
            }
        }
    }
}

// ---------------------------------------------------------------------------
// vtrans: Vb[bsh][l(1024)][64] -> Vt[bsh][d(64)][l(1024)]  (bf16)
// ---------------------------------------------------------------------------
__global__ __launch_bounds__(256)
void vtrans_kernel(const unsigned short* __restrict__ Vb, unsigned short* __restrict__ Vt)
{
    __shared__ short T[64][65];
    const int bsh = blockIdx.x, lc = blockIdx.y;
    const int tid = threadIdx.x;
    const int rr = tid >> 2, cc = (tid & 3) * 16;
    const short* src = (const short*)(Vb + ((size_t)bsh * 1024 + lc * 64 + rr) * 64 + cc);
    short8 a = ((const short8*)src)[0], b = ((const short8*)src)[1];
#pragma unroll
    for (int i = 0; i < 8; i++) { T[rr][cc + i] = a[i]; T[rr][cc + 8 + i] = b[i]; }
    __syncthreads();
    short8 oA, oB;
#pragma unroll
    for (int i = 0; i < 8; i++) { oA[i] = T[cc + i][rr]; oB[i] = T[cc + 8 + i][rr]; }
    short* dst = (short*)(Vt + ((size_t)bsh * 64 + rr) * 1024 + lc * 64 + cc);
    ((short8*)dst)[0] = oA; ((short8*)dst)[1] = oB;
}

// ---------------------------------------------------------------------------
// MFMA flash attention, 32x32x16, swapped QK^T.
// Block = 4 waves; wave owns 32 q-rows; KV tiles of 64 in LDS (swizzled).
// Writes ctx hi/lo bf16 [token][2048].
// ---------------------------------------------------------------------------
#define ATTN_SC 0.125f

__global__ __launch_bounds__(256)
void attn_mfma_kernel(const unsigned short* __restrict__ Qb,
                      const unsigned short* __restrict__ Kb,
                      const unsigned short* __restrict__ Vt,
                      unsigned short* __restrict__ ctx)
{
    __shared__ __align__(16) char Ks[8192];   // K[key][d] tile, swizzled
    __shared__ __align__(16) char Vs[8192];   // V^T[d][key] tile, swizzled

    const int id  = blockIdx.x;               // id%8 == bsh&7 (XCD affinity)
    const int bsh = (id >> 6) * 8 + (id & 7); // 0..127
    const int qc  = (id >> 3) & 7;            // 0..7
    const int bseg = bsh >> 4, h = bsh & 15;
    const int tid = threadIdx.x;
    const int w = tid >> 6, l = tid & 63;
    const int H = l >> 5, lq = l & 31;
    const int q0 = qc * 128 + w * 32;

    const size_t hbytes = (size_t)bsh << 17;  // bsh * 65536 elems * 2B

    // Q B-fragments (col=lq, k=H*8+e within each 16-k step), kept in regs
    short8 qf[4];
    {
        const char* qsrc = (const char*)Qb + hbytes + (size_t)(q0 + lq) * 128;
#pragma unroll
        for (int ks = 0; ks < 4; ks++)
            qf[ks] = *reinterpret_cast<const short8*>(qsrc + ks * 32 + H * 16);
    }

    f32x16 o0, o1;
#pragma unroll
    for (int r = 0; r < 16; r++) { o0[r] = 0.f; o1[r] = 0.f; }
    float m = -1e30f, lsum = 0.f;

    for (int t = 0; t < 16; t++) {
        // ---- stage K tile + V^T tile (8 KB each = 8 gld16 calls each) ----
#pragma unroll
        for (int p = 0; p < 2; p++) {
            const int c = w + p * 4;                 // 0..7
            const int o = c * 1024 + l * 16;         // byte offset in tile
            const int row  = o >> 7;                 // key (K) / d (V^T)
            const int colb = (o & 127) ^ ((l >> 3) << 4);   // pre-swizzled src
            gld16((const char*)Kb + hbytes + (size_t)(t * 64 + row) * 128 + colb,
                  Ks + c * 1024);
            gld16((const char*)Vt + hbytes + (size_t)row * 2048 + t * 128 + colb,
                  Vs + c * 1024);
        }
        __syncthreads();

        // ---- S^T = mfma(K, Q): rows=keys, col=q (=lq) ----
        f32x16 s0, s1;
#pragma unroll
        for (int r = 0; r < 16; r++) { s0[r] = 0.f; s1[r] = 0.f; }
#pragma unroll
        for (int ks = 0; ks < 4; ks++) {
            const int b0 = (lq * 128 + ks * 32 + H * 16) ^ ((lq & 7) << 4);
            short8 k0 = *reinterpret_cast<const short8*>(Ks + b0);
            short8 k1 = *reinterpret_cast<const short8*>(Ks + b0 + 4096);
            s0 = __builtin_amdgcn_mfma_f32_32x32x16_bf16(k0, qf[ks], s0, 0, 0, 0);
            s1 = __builtin_amdgcn_mfma_f32_32x32x16_bf16(k1, qf[ks], s1, 0, 0, 0);
        }

        // ---- online softmax (q = lq; keys split across lane halves) ----
        float tv[32];
#pragma unroll
        for (int r = 0; r < 16; r++) {
            tv[r]      = s0[r] * ATTN_SC;
            tv[16 + r] = s1[r] * ATTN_SC;
        }
        float tmax = tv[0];
#pragma unroll
        for (int r = 1; r < 32; r++) tmax = fmaxf(tmax, tv[r]);
        tmax = fmaxf(tmax, __shfl_xor(tmax, 32));
        const float mnew = fmaxf(m, tmax);
        if (__any(mnew > m)) {
            const float corr = __expf(m - mnew);
            lsum *= corr;
            m = mnew;
#pragma unroll
            for (int r = 0; r < 16; r++) {
                const float cr = __shfl(corr, (r & 3) + 8 * (r >> 2) + 4 * H);
                o0[r] *= cr; o1[r] *= cr;
            }
        }
        float pv[32];
        float ps = 0.f;
#pragma unroll
        for (int r = 0; r < 32; r++) { pv[r] = __expf(tv[r] - m); ps += pv[r]; }
        lsum += ps;

        // ---- P redistribution (pack + half-swap) + PV MFMAs ----
#pragma unroll
        for (int kf = 0; kf < 2; kf++) {
            unsigned c8[8], x8[8];
#pragma unroll
            for (int i = 0; i < 8; i++)
                c8[i] = (unsigned)f2bf_rne(pv[kf * 16 + 2 * i]) |
                        ((unsigned)f2bf_rne(pv[kf * 16 + 2 * i + 1]) << 16);
#pragma unroll
            for (int i = 0; i < 8; i++)
                x8[i] = (unsigned)__shfl_xor((int)c8[i], 32);
#pragma unroll
            for (int tt = 0; tt < 2; tt++) {
                const int b = tt * 4;
                union { unsigned u[4]; short8 v; } pa;
                pa.u[0] = H ? x8[b + 2] : c8[b + 0];
                pa.u[1] = H ? x8[b + 3] : c8[b + 1];
                pa.u[2] = H ? c8[b + 2] : x8[b + 0];
                pa.u[3] = H ? c8[b + 3] : x8[b + 1];
                const int vb0 = (lq * 128 + kf * 64 + tt * 32 + H * 16) ^ ((lq & 7) << 4);
                short8 v0 = *reinterpret_cast<const short8*>(Vs + vb0);
                short8 v1 = *reinterpret_cast<const short8*>(Vs + vb0 + 4096);
                o0 = __builtin_amdgcn_mfma_f32_32x32x16_bf16(pa.v, v0, o0, 0, 0, 0);
                o1 = __builtin_amdgcn_mfma_f32_32x32x16_bf16(pa.v, v1, o1, 0, 0, 0);
            }
        }
        __syncthreads();
    }

    // ---- epilogue: normalize, split hi/lo, store ----
    const float lt = lsum + __shfl_xor(lsum, 32);
#pragma unroll
    for (int r = 0; r < 16; r++) {
        const int qrow = (r & 3) + 8 * (r >> 2) + 4 * H;
        const float inv = 1.f / __shfl(lt, qrow);
        const size_t tok = (size_t)bseg * 1024 + q0 + qrow;
        unsigned short* p0 = ctx + tok * 2048 + h * 64 + lq;
        const float v0f = o0[r] * inv, v1f = o1[r] * inv;
        const unsigned short h0 = f2bf_rne(v0f);
        const unsigned short h1 = f2bf_rne(v1f);
        p0[0]    = h0;
        p0[32]   = h1;
        p0[1024] = f2bf_rne(v0f - bf2f(h0));
        p0[1056] = f2bf_rne(v1f - bf2f(h1));
    }
}

// ---------------------------------------------------------------------------
extern "C" void kernel_launch(void* const* d_in, const int* in_sizes, int n_in,
                              void* d_out, int out_size, void* d_ws, size_t ws_size,
                              hipStream_t stream)
{
    const float* x    = (const float*)d_in[0];
    const float* Wqkv = (const float*)d_in[1];
    const float* bqkv = (const float*)d_in[2];
    const float* Wout = (const float*)d_in[3];
    const float* bout = (const float*)d_in[4];
    float* out = (float*)d_out;

    // workspace layout (144 MB)
    char* ws = (char*)d_ws;
    unsigned short* Ax  = (unsigned short*)(ws);                    // 32 MB
    unsigned short* Wqt = (unsigned short*)(ws + 33554432);         // 12 MB
    unsigned short* Wot = (unsigned short*)(ws + 46137344);         //  4 MB
    unsigned short* Qb  = (unsigned short*)(ws + 50331648);         // 16 MB
    unsigned short* Kb  = (unsigned short*)(ws + 67108864);         // 16 MB
    unsigned short* Vb  = (unsigned short*)(ws + 83886080);         // 16 MB
    unsigned short* Vt  = (unsigned short*)(ws + 100663296);        // 16 MB
    unsigned short* ctx = (unsigned short*)(ws + 117440512);        // 32 MB

    prep_x_kernel<<<TOKENS, 256, 0, stream>>>(x, Ax);
    prep_w_kernel<<<dim3(96, 32), 256, 0, stream>>>(Wqkv, Wqt, 3072);
    prep_w_kernel<<<dim3(32, 32), 256, 0, stream>>>(Wout, Wot, 1024);

    // QKV projection -> q/k/v bf16 head-major
    mfma_gemm_kernel<1><<<dim3(24, 64), 256, 0, stream>>>(
        Ax, Wqt, bqkv, (float*)nullptr, Qb, Kb, Vb, 3072);

    vtrans_kernel<<<dim3(128, 16), 256, 0, stream>>>(Vb, Vt);

    attn_mfma_kernel<<<1024, 256, 0, stream>>>(Qb, Kb, Vt, ctx);

    // output projection -> fp32 out
    mfma_gemm_kernel<0><<<dim3(8, 64), 256, 0, stream>>>(
        ctx, Wot, bout, out, (unsigned short*)nullptr,
        (unsigned short*)nullptr, (unsigned short*)nullptr, 1024);
}

// Round 4
// 367.344 us; speedup vs baseline: 4.2684x; 1.0583x over previous
//
#include <hip/hip_runtime.h>
#include <hip/hip_bf16.h>

// DilatedAttention: B=2, S=8192, D=1024, H=16, hd=64, SEGMENT=2048, DILATION=2
// -> n_seg=4, L=1024, tokens = 8192. Gathered x row for token t:
//   xrow = (t>>10)*2048 + (t&1023)*2
#define TOKENS  8192

typedef short  short8 __attribute__((ext_vector_type(8)));
typedef float  f32x4  __attribute__((ext_vector_type(4)));
typedef float  f32x16 __attribute__((ext_vector_type(16)));
typedef unsigned short us4 __attribute__((ext_vector_type(4)));

__device__ __forceinline__ unsigned short f2bf_rne(float f) {
    unsigned u = __float_as_uint(f);
    unsigned r = (u + 0x7FFFu + ((u >> 16) & 1u)) >> 16;
    return (unsigned short)r;
}
__device__ __forceinline__ float bf2f(unsigned short h) {
    return __uint_as_float((unsigned)h << 16);
}
__device__ __forceinline__ void gld16(const void* gptr, void* lptr) {
    __builtin_amdgcn_global_load_lds(
        (const __attribute__((address_space(1))) void*)gptr,
        (__attribute__((address_space(3))) void*)lptr, 16, 0, 0);
}

// ---------------------------------------------------------------------------
// prep_x: gather + fp32 -> bf16 hi/lo split.  Ax[t][k]=hi, Ax[t][1024+k]=lo
// ---------------------------------------------------------------------------
__global__ __launch_bounds__(256)
void prep_x_kernel(const float* __restrict__ x, unsigned short* __restrict__ Ax)
{
    const int t = blockIdx.x;
    const int c = threadIdx.x * 4;
    const long xrow = (long)((t >> 10) * 2048 + (t & 1023) * 2);
    float4 v = *reinterpret_cast<const float4*>(&x[xrow * 1024 + c]);
    float f[4] = {v.x, v.y, v.z, v.w};
    us4 hv, lv;
#pragma unroll
    for (int u = 0; u < 4; u++) {
        unsigned short hi = f2bf_rne(f[u]);
        hv[u] = hi;
        lv[u] = f2bf_rne(f[u] - bf2f(hi));
    }
    *reinterpret_cast<us4*>(&Ax[(size_t)t * 2048 + c]) = hv;
    *reinterpret_cast<us4*>(&Ax[(size_t)t * 2048 + 1024 + c]) = lv;
}

// ---------------------------------------------------------------------------
// prep_w: W[1024][N] fp32 -> Wt[N][2048] bf16 (transposed, hi|lo along k)
// ---------------------------------------------------------------------------
__global__ __launch_bounds__(256)
void prep_w_kernel(const float* __restrict__ W, unsigned short* __restrict__ Wt, int N)
{
    __shared__ float T[32][33];
    const int n0 = blockIdx.x * 32, k0 = blockIdx.y * 32;
    const int tid = threadIdx.x;
#pragma unroll
    for (int p = 0; p < 4; p++) {
        int r = p * 8 + (tid >> 5), c = tid & 31;
        T[r][c] = W[(long)(k0 + r) * N + n0 + c];
    }
    __syncthreads();
#pragma unroll
    for (int p = 0; p < 4; p++) {
        int on = p * 8 + (tid >> 5), ok = tid & 31;
        float v = T[ok][on];
        unsigned short hi = f2bf_rne(v);
        unsigned short lo = f2bf_rne(v - bf2f(hi));
        Wt[(size_t)(n0 + on) * 2048 + k0 + ok] = hi;
        Wt[(size_t)(n0 + on) * 2048 + 1024 + k0 + ok] = lo;
    }
}

// ---------------------------------------------------------------------------
// bf16x3 MFMA GEMM, deep-pipelined (T2+T3+T4+T5):
//   BM=128, BN=256, BK=64, 512 threads (8 waves 2Mx4N), 64x64 out/wave.
//   Triple-buffered LDS (3 x 48KB), prefetch distance 2, counted vmcnt(6)
//   at tile boundaries (never drains in-flight prefetch). 4 phases/K-tile,
//   8 MFMA each, raw s_barrier (no vmcnt drain), setprio around MFMA.
//   LDS rows are 128B -> XOR-swizzle byte^((row&7)<<4), staged via
//   pre-swizzled global source chunk cg=(l&7)^(l>>3) (both-sides involution).
// K runs 3 segments (Ahi*Bhi, Alo*Bhi, Ahi*Blo) x 1024 = 48 K-tiles of 64.
// EPI=0: C fp32 = A*B + bias.  EPI=1: QKV epilogue -> q/k/v bf16 head-major.
// ---------------------------------------------------------------------------
template<int EPI>
__global__ __launch_bounds__(512, 2)
void gemm8p_kernel(const unsigned short* __restrict__ A,
                   const unsigned short* __restrict__ Bt,
                   const float* __restrict__ bias,
                   float* __restrict__ C,
                   unsigned short* __restrict__ Qb,
                   unsigned short* __restrict__ Kb,
                   unsigned short* __restrict__ Vb,
                   int N, int NBX)
{
    __shared__ __align__(16) char lds[3 * 49152];   // 144 KB

    const int tid = threadIdx.x;
    const int l = tid & 63, w = tid >> 6;
    const int wm = w >> 2, wn = w & 3;
    const int l15 = l & 15;

    // XCD-aware bijective swizzle (gridDim.x % 8 == 0 by construction)
    const int nwg = gridDim.x;
    const int cpx = nwg >> 3;
    const int bidr = blockIdx.x;
    const int wg = (bidr & 7) * cpx + (bidr >> 3);
    const int by = wg / NBX, bx = wg - by * NBX;
    const int trow0 = by * 128, col0 = bx * 256;

    // staging lane constants (pre-swizzled global source)
    const int lr8 = l >> 3;                  // row within 8-row chunk
    const int cg  = (l & 7) ^ lr8;           // global 16B-chunk index
    const size_t aBase = (size_t)(trow0 + w * 16 + lr8) * 2048 + cg * 8;
    const size_t bBase = (size_t)(col0  + w * 32 + lr8) * 2048 + cg * 8;

    // fragment-read lane constants (swizzled in-row byte offsets, h=0/1)
    const int offs0 = (((l >> 4) * 16)      ) ^ ((l & 7) << 4);
    const int offs1 = (((l >> 4) * 16) + 64 ) ^ ((l & 7) << 4);

    f32x4 acc[4][4];
#pragma unroll
    for (int i = 0; i < 4; i++)
#pragma unroll
        for (int j = 0; j < 4; j++) acc[i][j] = (f32x4){0.f, 0.f, 0.f, 0.f};

    // ---- prologue: stage K-tiles 0 and 1 (6 gld16 per wave per tile) ----
#pragma unroll
    for (int t0 = 0; t0 < 2; ++t0) {
        const int ac = t0 * 64;              // seg 0: acol = bcol = k0
        char* bufA = lds + t0 * 49152;
        char* bufB = bufA + 16384;
#pragma unroll
        for (int p = 0; p < 2; ++p)
            gld16(&A[aBase + (size_t)p * (8 * 2048) + ac], bufA + (w * 2 + p) * 1024);
#pragma unroll
        for (int p = 0; p < 4; ++p)
            gld16(&Bt[bBase + (size_t)p * (8 * 2048) + ac], bufB + (w * 4 + p) * 1024);
    }
    asm volatile("s_waitcnt vmcnt(6)" ::: "memory");   // tile 0 landed
    __builtin_amdgcn_s_barrier();

    int bc = 0;
    for (int t = 0; t < 48; ++t) {
        char* bufA = lds + bc * 49152;
        char* bufB = bufA + 16384;
        const int bcn = (bc == 0) ? 2 : bc - 1;        // (t+2) % 3
        char* nbufA = lds + bcn * 49152;
        char* nbufB = nbufA + 16384;

        const int tp = t + 2;
        const bool pf = (tp < 48);
        int acp = 0, bcp = 0;
        if (pf) {
            const int seg = tp >> 4, k0 = (tp & 15) * 64;
            acp = ((seg == 1) ? 1024 : 0) + k0;        // ASEL = {hi, lo, hi}
            bcp = ((seg == 2) ? 1024 : 0) + k0;        // BSEL = {hi, hi, lo}
        }

#pragma unroll
        for (int p = 0; p < 4; ++p) {
            const int pm = p >> 1, pn = p & 1;

            // ---- ds_read this phase's fragments (quadrant, both k-halves)
            short8 af[2][2], bfv[2][2];
#pragma unroll
            for (int i = 0; i < 2; ++i) {
                const int r = wm * 64 + (pm * 2 + i) * 16 + l15;
                af[i][0] = *reinterpret_cast<const short8*>(bufA + r * 128 + offs0);
                af[i][1] = *reinterpret_cast<const short8*>(bufA + r * 128 + offs1);
            }
#pragma unroll
            for (int j = 0; j < 2; ++j) {
                const int r = wn * 64 + (pn * 2 + j) * 16 + l15;
                bfv[j][0] = *reinterpret_cast<const short8*>(bufB + r * 128 + offs0);
                bfv[j][1] = *reinterpret_cast<const short8*>(bufB + r * 128 + offs1);
            }

            // ---- issue prefetch for tile t+2 (2 chunks/phase, phases 0-2)
            if (pf) {
                if (p == 0) {
                    gld16(&A[aBase + acp],            nbufA + (w * 2 + 0) * 1024);
                    gld16(&A[aBase + 8 * 2048 + acp], nbufA + (w * 2 + 1) * 1024);
                } else if (p == 1) {
                    gld16(&Bt[bBase + bcp],            nbufB + (w * 4 + 0) * 1024);
                    gld16(&Bt[bBase + 8 * 2048 + bcp], nbufB + (w * 4 + 1) * 1024);
                } else if (p == 2) {
                    gld16(&Bt[bBase + 16 * 2048 + bcp], nbufB + (w * 4 + 2) * 1024);
                    gld16(&Bt[bBase + 24 * 2048 + bcp], nbufB + (w * 4 + 3) * 1024);
                }
            }

            // ---- MFMA cluster
            __builtin_amdgcn_s_setprio(1);
#pragma unroll
            for (int h = 0; h < 2; ++h)
#pragma unroll
                for (int i = 0; i < 2; ++i)
#pragma unroll
                    for (int j = 0; j < 2; ++j)
                        acc[pm * 2 + i][pn * 2 + j] =
                            __builtin_amdgcn_mfma_f32_16x16x32_bf16(
                                af[i][h], bfv[j][h], acc[pm * 2 + i][pn * 2 + j],
                                0, 0, 0);
            __builtin_amdgcn_s_setprio(0);
            __builtin_amdgcn_s_barrier();
        }

        // ---- tile boundary: counted vmcnt (only t+1's loads must be done)
        if (pf) asm volatile("s_waitcnt vmcnt(6)" ::: "memory");
        else    asm volatile("s_waitcnt vmcnt(0)" ::: "memory");
        __builtin_amdgcn_s_barrier();
        bc = (bc == 2) ? 0 : bc + 1;
    }

    // ---- epilogue ----
    // C/D layout (verified m89/m91): col = lane&15, row = (lane>>4)*4 + reg
#pragma unroll
    for (int j = 0; j < 4; ++j) {
        const int gc = col0 + wn * 64 + j * 16 + l15;
        const float bv = bias[gc];
        if (EPI == 0) {
#pragma unroll
            for (int i = 0; i < 4; ++i) {
                const int gr0 = trow0 + wm * 64 + i * 16 + (l >> 4) * 4;
#pragma unroll
                for (int r = 0; r < 4; ++r)
                    C[(size_t)(gr0 + r) * N + gc] = acc[i][j][r] + bv;
            }
        } else {
            const int which = gc >> 10;
            const int head  = (gc >> 6) & 15;
            const int d     = gc & 63;
            unsigned short* dst = (which == 0) ? Qb : ((which == 1) ? Kb : Vb);
#pragma unroll
            for (int i = 0; i < 4; ++i) {
                const int gr0 = trow0 + wm * 64 + i * 16 + (l >> 4) * 4;
#pragma unroll
                for (int r = 0; r < 4; ++r) {
                    const int gr = gr0 + r;
                    const size_t adr = ((size_t)((gr >> 10) * 16 + head) << 16)
                                     + (size_t)(gr & 1023) * 64 + d;
                    dst[adr] = f2bf_rne(acc[i][j][r] + bv);
                }
            }
        }
    }
}

// ---------------------------------------------------------------------------
// vtrans: Vb[bsh][l(1024)][64] -> Vt[bsh][d(64)][l(1024)]  (bf16)
// ---------------------------------------------------------------------------
__global__ __launch_bounds__(256)
void vtrans_kernel(const unsigned short* __restrict__ Vb, unsigned short* __restrict__ Vt)
{
    __shared__ short T[64][65];
    const int bsh = blockIdx.x, lc = blockIdx.y;
    const int tid = threadIdx.x;
    const int rr = tid >> 2, cc = (tid & 3) * 16;
    const short* src = (const short*)(Vb + ((size_t)bsh * 1024 + lc * 64 + rr) * 64 + cc);
    short8 a = ((const short8*)src)[0], b = ((const short8*)src)[1];
#pragma unroll
    for (int i = 0; i < 8; i++) { T[rr][cc + i] = a[i]; T[rr][cc + 8 + i] = b[i]; }
    __syncthreads();
    short8 oA, oB;
#pragma unroll
    for (int i = 0; i < 8; i++) { oA[i] = T[cc + i][rr]; oB[i] = T[cc + 8 + i][rr]; }
    short* dst = (short*)(Vt + ((size_t)bsh * 64 + rr) * 1024 + lc * 64 + cc);
    ((short8*)dst)[0] = oA; ((short8*)dst)[1] = oB;
}

// ---------------------------------------------------------------------------
// MFMA flash attention, 32x32x16, swapped QK^T.
// Block = 4 waves; wave owns 32 q-rows; KV tiles of 64 in LDS (swizzled).
// Writes ctx hi/lo bf16 [token][2048].
// ---------------------------------------------------------------------------
#define ATTN_SC 0.125f

__global__ __launch_bounds__(256)
void attn_mfma_kernel(const unsigned short* __restrict__ Qb,
                      const unsigned short* __restrict__ Kb,
                      const unsigned short* __restrict__ Vt,
                      unsigned short* __restrict__ ctx)
{
    __shared__ __align__(16) char Ks[8192];   // K[key][d] tile, swizzled
    __shared__ __align__(16) char Vs[8192];   // V^T[d][key] tile, swizzled

    const int id  = blockIdx.x;               // id%8 == bsh&7 (XCD affinity)
    const int bsh = (id >> 6) * 8 + (id & 7); // 0..127
    const int qc  = (id >> 3) & 7;            // 0..7
    const int bseg = bsh >> 4, h = bsh & 15;
    const int tid = threadIdx.x;
    const int w = tid >> 6, l = tid & 63;
    const int H = l >> 5, lq = l & 31;
    const int q0 = qc * 128 + w * 32;

    const size_t hbytes = (size_t)bsh << 17;  // bsh * 65536 elems * 2B

    // Q B-fragments (col=lq, k=H*8+e within each 16-k step), kept in regs
    short8 qf[4];
    {
        const char* qsrc = (const char*)Qb + hbytes + (size_t)(q0 + lq) * 128;
#pragma unroll
        for (int ks = 0; ks < 4; ks++)
            qf[ks] = *reinterpret_cast<const short8*>(qsrc + ks * 32 + H * 16);
    }

    f32x16 o0, o1;
#pragma unroll
    for (int r = 0; r < 16; r++) { o0[r] = 0.f; o1[r] = 0.f; }
    float m = -1e30f, lsum = 0.f;

    for (int t = 0; t < 16; t++) {
        // ---- stage K tile + V^T tile (8 KB each = 8 gld16 calls each) ----
#pragma unroll
        for (int p = 0; p < 2; p++) {
            const int c = w + p * 4;                 // 0..7
            const int o = c * 1024 + l * 16;         // byte offset in tile
            const int row  = o >> 7;                 // key (K) / d (V^T)
            const int colb = (o & 127) ^ ((l >> 3) << 4);   // pre-swizzled src
            gld16((const char*)Kb + hbytes + (size_t)(t * 64 + row) * 128 + colb,
                  Ks + c * 1024);
            gld16((const char*)Vt + hbytes + (size_t)row * 2048 + t * 128 + colb,
                  Vs + c * 1024);
        }
        __syncthreads();

        // ---- S^T = mfma(K, Q): rows=keys, col=q (=lq) ----
        f32x16 s0, s1;
#pragma unroll
        for (int r = 0; r < 16; r++) { s0[r] = 0.f; s1[r] = 0.f; }
#pragma unroll
        for (int ks = 0; ks < 4; ks++) {
            const int b0 = (lq * 128 + ks * 32 + H * 16) ^ ((lq & 7) << 4);
            short8 k0 = *reinterpret_cast<const short8*>(Ks + b0);
            short8 k1 = *reinterpret_cast<const short8*>(Ks + b0 + 4096);
            s0 = __builtin_amdgcn_mfma_f32_32x32x16_bf16(k0, qf[ks], s0, 0, 0, 0);
            s1 = __builtin_amdgcn_mfma_f32_32x32x16_bf16(k1, qf[ks], s1, 0, 0, 0);
        }

        // ---- online softmax (q = lq; keys split across lane halves) ----
        float tv[32];
#pragma unroll
        for (int r = 0; r < 16; r++) {
            tv[r]      = s0[r] * ATTN_SC;
            tv[16 + r] = s1[r] * ATTN_SC;
        }
        float tmax = tv[0];
#pragma unroll
        for (int r = 1; r < 32; r++) tmax = fmaxf(tmax, tv[r]);
        tmax = fmaxf(tmax, __shfl_xor(tmax, 32));
        const float mnew = fmaxf(m, tmax);
        if (__any(mnew > m)) {
            const float corr = __expf(m - mnew);
            lsum *= corr;
            m = mnew;
#pragma unroll
            for (int r = 0; r < 16; r++) {
                const float cr = __shfl(corr, (r & 3) + 8 * (r >> 2) + 4 * H);
                o0[r] *= cr; o1[r] *= cr;
            }
        }
        float pv[32];
        float ps = 0.f;
#pragma unroll
        for (int r = 0; r < 32; r++) { pv[r] = __expf(tv[r] - m); ps += pv[r]; }
        lsum += ps;

        // ---- P redistribution (pack + half-swap) + PV MFMAs ----
#pragma unroll
        for (int kf = 0; kf < 2; kf++) {
            unsigned c8[8], x8[8];
#pragma unroll
            for (int i = 0; i < 8; i++)
                c8[i] = (unsigned)f2bf_rne(pv[kf * 16 + 2 * i]) |
                        ((unsigned)f2bf_rne(pv[kf * 16 + 2 * i + 1]) << 16);
#pragma unroll
            for (int i = 0; i < 8; i++)
                x8[i] = (unsigned)__shfl_xor((int)c8[i], 32);
#pragma unroll
            for (int tt = 0; tt < 2; tt++) {
                const int b = tt * 4;
                union { unsigned u[4]; short8 v; } pa;
                pa.u[0] = H ? x8[b + 2] : c8[b + 0];
                pa.u[1] = H ? x8[b + 3] : c8[b + 1];
                pa.u[2] = H ? c8[b + 2] : x8[b + 0];
                pa.u[3] = H ? c8[b + 3] : x8[b + 1];
                const int vb0 = (lq * 128 + kf * 64 + tt * 32 + H * 16) ^ ((lq & 7) << 4);
                short8 v0 = *reinterpret_cast<const short8*>(Vs + vb0);
                short8 v1 = *reinterpret_cast<const short8*>(Vs + vb0 + 4096);
                o0 = __builtin_amdgcn_mfma_f32_32x32x16_bf16(pa.v, v0, o0, 0, 0, 0);
                o1 = __builtin_amdgcn_mfma_f32_32x32x16_bf16(pa.v, v1, o1, 0, 0, 0);
            }
        }
        __syncthreads();
    }

    // ---- epilogue: normalize, split hi/lo, store ----
    const float lt = lsum + __shfl_xor(lsum, 32);
#pragma unroll
    for (int r = 0; r < 16; r++) {
        const int qrow = (r & 3) + 8 * (r >> 2) + 4 * H;
        const float inv = 1.f / __shfl(lt, qrow);
        const size_t tok = (size_t)bseg * 1024 + q0 + qrow;
        unsigned short* p0 = ctx + tok * 2048 + h * 64 + lq;
        const float v0f = o0[r] * inv, v1f = o1[r] * inv;
        const unsigned short h0 = f2bf_rne(v0f);
        const unsigned short h1 = f2bf_rne(v1f);
        p0[0]    = h0;
        p0[32]   = h1;
        p0[1024] = f2bf_rne(v0f - bf2f(h0));
        p0[1056] = f2bf_rne(v1f - bf2f(h1));
    }
}

// ---------------------------------------------------------------------------
extern "C" void kernel_launch(void* const* d_in, const int* in_sizes, int n_in,
                              void* d_out, int out_size, void* d_ws, size_t ws_size,
                              hipStream_t stream)
{
    const float* x    = (const float*)d_in[0];
    const float* Wqkv = (const float*)d_in[1];
    const float* bqkv = (const float*)d_in[2];
    const float* Wout = (const float*)d_in[3];
    const float* bout = (const float*)d_in[4];
    float* out = (float*)d_out;

    // workspace layout (144 MB)
    char* ws = (char*)d_ws;
    unsigned short* Ax  = (unsigned short*)(ws);                    // 32 MB
    unsigned short* Wqt = (unsigned short*)(ws + 33554432);         // 12 MB
    unsigned short* Wot = (unsigned short*)(ws + 46137344);         //  4 MB
    unsigned short* Qb  = (unsigned short*)(ws + 50331648);         // 16 MB
    unsigned short* Kb  = (unsigned short*)(ws + 67108864);         // 16 MB
    unsigned short* Vb  = (unsigned short*)(ws + 83886080);         // 16 MB
    unsigned short* Vt  = (unsigned short*)(ws + 100663296);        // 16 MB
    unsigned short* ctx = (unsigned short*)(ws + 117440512);        // 32 MB

    prep_x_kernel<<<TOKENS, 256, 0, stream>>>(x, Ax);
    prep_w_kernel<<<dim3(96, 32), 256, 0, stream>>>(Wqkv, Wqt, 3072);
    prep_w_kernel<<<dim3(32, 32), 256, 0, stream>>>(Wout, Wot, 1024);

    // QKV projection -> q/k/v bf16 head-major.  grid = (3072/256)*(8192/128)
    //   = 12*64 = 768 blocks (3 exact passes at 1 block/CU), %8 == 0.
    gemm8p_kernel<1><<<768, 512, 0, stream>>>(
        Ax, Wqt, bqkv, (float*)nullptr, Qb, Kb, Vb, 3072, 12);

    vtrans_kernel<<<dim3(128, 16), 256, 0, stream>>>(Vb, Vt);

    attn_mfma_kernel<<<1024, 256, 0, stream>>>(Qb, Kb, Vt, ctx);

    // output projection -> fp32 out.  grid = (1024/256)*(8192/128) = 256 (1 pass)
    gemm8p_kernel<0><<<256, 512, 0, stream>>>(
        ctx, Wot, bout, out, (unsigned short*)nullptr,
        (unsigned short*)nullptr, (unsigned short*)nullptr, 1024, 4);
}

// Round 5
// 274.703 us; speedup vs baseline: 5.7078x; 1.3372x over previous
//
#include <hip/hip_runtime.h>
#include <hip/hip_bf16.h>

// DilatedAttention: B=2, S=8192, D=1024, H=16, hd=64, SEGMENT=2048, DILATION=2
// -> n_seg=4, L=1024, tokens = 8192. Gathered x row for token t:
//   xrow = (t>>10)*2048 + (t&1023)*2
#define TOKENS  8192

typedef short  short8 __attribute__((ext_vector_type(8)));
typedef float  f32x4  __attribute__((ext_vector_type(4)));
typedef float  f32x16 __attribute__((ext_vector_type(16)));
typedef unsigned short us4 __attribute__((ext_vector_type(4)));

__device__ __forceinline__ unsigned short f2bf_rne(float f) {
    unsigned u = __float_as_uint(f);
    unsigned r = (u + 0x7FFFu + ((u >> 16) & 1u)) >> 16;
    return (unsigned short)r;
}
__device__ __forceinline__ float bf2f(unsigned short h) {
    return __uint_as_float((unsigned)h << 16);
}
__device__ __forceinline__ void gld16(const void* gptr, void* lptr) {
    __builtin_amdgcn_global_load_lds(
        (const __attribute__((address_space(1))) void*)gptr,
        (__attribute__((address_space(3))) void*)lptr, 16, 0, 0);
}

// ---------------------------------------------------------------------------
// prep_x: gather + fp32 -> bf16 hi/lo split.  Ax[t][k]=hi, Ax[t][1024+k]=lo
// ---------------------------------------------------------------------------
__global__ __launch_bounds__(256)
void prep_x_kernel(const float* __restrict__ x, unsigned short* __restrict__ Ax)
{
    const int t = blockIdx.x;
    const int c = threadIdx.x * 4;
    const long xrow = (long)((t >> 10) * 2048 + (t & 1023) * 2);
    float4 v = *reinterpret_cast<const float4*>(&x[xrow * 1024 + c]);
    float f[4] = {v.x, v.y, v.z, v.w};
    us4 hv, lv;
#pragma unroll
    for (int u = 0; u < 4; u++) {
        unsigned short hi = f2bf_rne(f[u]);
        hv[u] = hi;
        lv[u] = f2bf_rne(f[u] - bf2f(hi));
    }
    *reinterpret_cast<us4*>(&Ax[(size_t)t * 2048 + c]) = hv;
    *reinterpret_cast<us4*>(&Ax[(size_t)t * 2048 + 1024 + c]) = lv;
}

// ---------------------------------------------------------------------------
// prep_w: W[1024][N] fp32 -> Wt[N][1024] bf16 (transposed, hi only --
// bf16x2 scheme keeps A_hi*B_hi + A_lo*B_hi; A_hi*B_lo term is dropped,
// attention softmax damping makes it negligible at output level)
// ---------------------------------------------------------------------------
__global__ __launch_bounds__(256)
void prep_w_kernel(const float* __restrict__ W, unsigned short* __restrict__ Wt, int N)
{
    __shared__ float T[32][33];
    const int n0 = blockIdx.x * 32, k0 = blockIdx.y * 32;
    const int tid = threadIdx.x;
#pragma unroll
    for (int p = 0; p < 4; p++) {
        int r = p * 8 + (tid >> 5), c = tid & 31;
        T[r][c] = W[(long)(k0 + r) * N + n0 + c];
    }
    __syncthreads();
#pragma unroll
    for (int p = 0; p < 4; p++) {
        int on = p * 8 + (tid >> 5), ok = tid & 31;
        Wt[(size_t)(n0 + on) * 1024 + k0 + ok] = f2bf_rne(T[ok][on]);
    }
}

// ---------------------------------------------------------------------------
// bf16x2 MFMA GEMM, read-once fragments:
//   BM=128, BN=256, BK=64, 512 threads (8 waves 2Mx4N), 64x64 out/wave.
//   Triple-buffered LDS (3 x 48KB), prefetch distance 2, counted vmcnt(6)
//   at tile boundaries. ONE compute region per K-tile: 16 unique ds_read_b128
//   (each fragment read exactly once -> 0.5 reads/MFMA vs R4's 1.0), 32 MFMA,
//   prefetch issued at region top, one barrier per tile.
//   LDS rows 128B, XOR-swizzle byte^((row&7)<<4) via pre-swizzled global
//   source chunk cg=(l&7)^(l>>3) (both-sides involution; measured 0 conflicts).
// K runs 2 segments (Ahi*Bhi, Alo*Bhi) x 1024 = 32 K-tiles of 64.
// A stride 2048 (hi|lo), Bt stride 1024 (hi only).
// EPI=0: C fp32 = A*B + bias.  EPI=1: QKV epilogue -> q/k/v bf16 head-major.
// ---------------------------------------------------------------------------
template<int EPI>
__global__ __launch_bounds__(512, 2)
void gemm8p_kernel(const unsigned short* __restrict__ A,
                   const unsigned short* __restrict__ Bt,
                   const float* __restrict__ bias,
                   float* __restrict__ C,
                   unsigned short* __restrict__ Qb,
                   unsigned short* __restrict__ Kb,
                   unsigned short* __restrict__ Vb,
                   int N, int NBX)
{
    __shared__ __align__(16) char lds[3 * 49152];   // 144 KB

    const int tid = threadIdx.x;
    const int l = tid & 63, w = tid >> 6;
    const int wm = w >> 2, wn = w & 3;
    const int l15 = l & 15;

    // XCD-aware bijective swizzle (gridDim.x % 8 == 0 by construction)
    const int nwg = gridDim.x;
    const int cpx = nwg >> 3;
    const int bidr = blockIdx.x;
    const int wg = (bidr & 7) * cpx + (bidr >> 3);
    const int by = wg / NBX, bx = wg - by * NBX;
    const int trow0 = by * 128, col0 = bx * 256;

    // staging lane constants (pre-swizzled global source)
    const int lr8 = l >> 3;                  // row within 8-row chunk
    const int cg  = (l & 7) ^ lr8;           // global 16B-chunk index
    const size_t aBase = (size_t)(trow0 + w * 16 + lr8) * 2048 + cg * 8;
    const size_t bBase = (size_t)(col0  + w * 32 + lr8) * 1024 + cg * 8;

    // fragment-read lane constants (swizzled in-row byte offsets, k-halves)
    const int offs0 = (((l >> 4) * 16)     ) ^ ((l & 7) << 4);
    const int offs1 = (((l >> 4) * 16) + 64) ^ ((l & 7) << 4);

    f32x4 acc[4][4];
#pragma unroll
    for (int i = 0; i < 4; i++)
#pragma unroll
        for (int j = 0; j < 4; j++) acc[i][j] = (f32x4){0.f, 0.f, 0.f, 0.f};

    // ---- prologue: stage K-tiles 0 and 1 (6 gld16 per wave per tile) ----
#pragma unroll
    for (int t0 = 0; t0 < 2; ++t0) {
        const int ac = t0 * 64;              // seg 0: acol = bcol = k0
        char* bufA = lds + t0 * 49152;
        char* bufB = bufA + 16384;
#pragma unroll
        for (int p = 0; p < 2; ++p)
            gld16(&A[aBase + (size_t)p * (8 * 2048) + ac], bufA + (w * 2 + p) * 1024);
#pragma unroll
        for (int p = 0; p < 4; ++p)
            gld16(&Bt[bBase + (size_t)p * (8 * 1024) + ac], bufB + (w * 4 + p) * 1024);
    }
    asm volatile("s_waitcnt vmcnt(6)" ::: "memory");   // tile 0 landed
    __builtin_amdgcn_s_barrier();

    int bc = 0;
    for (int t = 0; t < 32; ++t) {
        char* bufA = lds + bc * 49152;
        char* bufB = bufA + 16384;
        const int bcn = (bc == 0) ? 2 : bc - 1;        // (t+2) % 3
        char* nbufA = lds + bcn * 49152;
        char* nbufB = nbufA + 16384;

        const int tp = t + 2;
        const bool pf = (tp < 32);

        // ---- issue prefetch for tile t+2 at region top (max latency cover)
        if (pf) {
            const int k0  = (tp & 15) * 64;
            const int acp = ((tp >> 4) ? 1024 : 0) + k0;   // seg1 -> A-lo
            const int bcp = k0;                            // B always hi
            gld16(&A[aBase + acp],            nbufA + (w * 2 + 0) * 1024);
            gld16(&A[aBase + 8 * 2048 + acp], nbufA + (w * 2 + 1) * 1024);
#pragma unroll
            for (int p = 0; p < 4; ++p)
                gld16(&Bt[bBase + (size_t)p * (8 * 1024) + bcp],
                      nbufB + (w * 4 + p) * 1024);
        }

        // ---- read all 16 unique fragments once ----
        short8 af[4][2], bf[4][2];
#pragma unroll
        for (int i = 0; i < 4; ++i) {
            const int r = wm * 64 + i * 16 + l15;
            af[i][0] = *reinterpret_cast<const short8*>(bufA + r * 128 + offs0);
            af[i][1] = *reinterpret_cast<const short8*>(bufA + r * 128 + offs1);
        }
#pragma unroll
        for (int j = 0; j < 4; ++j) {
            const int r = wn * 64 + j * 16 + l15;
            bf[j][0] = *reinterpret_cast<const short8*>(bufB + r * 128 + offs0);
            bf[j][1] = *reinterpret_cast<const short8*>(bufB + r * 128 + offs1);
        }

        // ---- 32 MFMA ----
        __builtin_amdgcn_s_setprio(1);
#pragma unroll
        for (int i = 0; i < 4; ++i)
#pragma unroll
            for (int j = 0; j < 4; ++j) {
                acc[i][j] = __builtin_amdgcn_mfma_f32_16x16x32_bf16(
                    af[i][0], bf[j][0], acc[i][j], 0, 0, 0);
                acc[i][j] = __builtin_amdgcn_mfma_f32_16x16x32_bf16(
                    af[i][1], bf[j][1], acc[i][j], 0, 0, 0);
            }
        __builtin_amdgcn_s_setprio(0);

        // ---- tile boundary: counted vmcnt (only t+1's loads must be done)
        if (pf) asm volatile("s_waitcnt vmcnt(6)" ::: "memory");
        else    asm volatile("s_waitcnt vmcnt(0)" ::: "memory");
        __builtin_amdgcn_s_barrier();
        bc = (bc == 2) ? 0 : bc + 1;
    }

    // ---- epilogue ----
    // C/D layout (verified m89/m91): col = lane&15, row = (lane>>4)*4 + reg
#pragma unroll
    for (int j = 0; j < 4; ++j) {
        const int gc = col0 + wn * 64 + j * 16 + l15;
        const float bv = bias[gc];
        if (EPI == 0) {
#pragma unroll
            for (int i = 0; i < 4; ++i) {
                const int gr0 = trow0 + wm * 64 + i * 16 + (l >> 4) * 4;
#pragma unroll
                for (int r = 0; r < 4; ++r)
                    C[(size_t)(gr0 + r) * N + gc] = acc[i][j][r] + bv;
            }
        } else {
            const int which = gc >> 10;
            const int head  = (gc >> 6) & 15;
            const int d     = gc & 63;
            unsigned short* dst = (which == 0) ? Qb : ((which == 1) ? Kb : Vb);
#pragma unroll
            for (int i = 0; i < 4; ++i) {
                const int gr0 = trow0 + wm * 64 + i * 16 + (l >> 4) * 4;
#pragma unroll
                for (int r = 0; r < 4; ++r) {
                    const int gr = gr0 + r;
                    const size_t adr = ((size_t)((gr >> 10) * 16 + head) << 16)
                                     + (size_t)(gr & 1023) * 64 + d;
                    dst[adr] = f2bf_rne(acc[i][j][r] + bv);
                }
            }
        }
    }
}

// ---------------------------------------------------------------------------
// vtrans: Vb[bsh][l(1024)][64] -> Vt[bsh][d(64)][l(1024)]  (bf16)
// ---------------------------------------------------------------------------
__global__ __launch_bounds__(256)
void vtrans_kernel(const unsigned short* __restrict__ Vb, unsigned short* __restrict__ Vt)
{
    __shared__ short T[64][65];
    const int bsh = blockIdx.x, lc = blockIdx.y;
    const int tid = threadIdx.x;
    const int rr = tid >> 2, cc = (tid & 3) * 16;
    const short* src = (const short*)(Vb + ((size_t)bsh * 1024 + lc * 64 + rr) * 64 + cc);
    short8 a = ((const short8*)src)[0], b = ((const short8*)src)[1];
#pragma unroll
    for (int i = 0; i < 8; i++) { T[rr][cc + i] = a[i]; T[rr][cc + 8 + i] = b[i]; }
    __syncthreads();
    short8 oA, oB;
#pragma unroll
    for (int i = 0; i < 8; i++) { oA[i] = T[cc + i][rr]; oB[i] = T[cc + 8 + i][rr]; }
    short* dst = (short*)(Vt + ((size_t)bsh * 64 + rr) * 1024 + lc * 64 + cc);
    ((short8*)dst)[0] = oA; ((short8*)dst)[1] = oB;
}

// ---------------------------------------------------------------------------
// MFMA flash attention, 32x32x16, swapped QK^T.
// Block = 4 waves; wave owns 32 q-rows; KV tiles of 64 in LDS (swizzled).
// Writes ctx hi/lo bf16 [token][2048].
// ---------------------------------------------------------------------------
#define ATTN_SC 0.125f

__global__ __launch_bounds__(256)
void attn_mfma_kernel(const unsigned short* __restrict__ Qb,
                      const unsigned short* __restrict__ Kb,
                      const unsigned short* __restrict__ Vt,
                      unsigned short* __restrict__ ctx)
{
    __shared__ __align__(16) char Ks[8192];   // K[key][d] tile, swizzled
    __shared__ __align__(16) char Vs[8192];   // V^T[d][key] tile, swizzled

    const int id  = blockIdx.x;               // id%8 == bsh&7 (XCD affinity)
    const int bsh = (id >> 6) * 8 + (id & 7); // 0..127
    const int qc  = (id >> 3) & 7;            // 0..7
    const int bseg = bsh >> 4, h = bsh & 15;
    const int tid = threadIdx.x;
    const int w = tid >> 6, l = tid & 63;
    const int H = l >> 5, lq = l & 31;
    const int q0 = qc * 128 + w * 32;

    const size_t hbytes = (size_t)bsh << 17;  // bsh * 65536 elems * 2B

    // Q B-fragments (col=lq, k=H*8+e within each 16-k step), kept in regs
    short8 qf[4];
    {
        const char* qsrc = (const char*)Qb + hbytes + (size_t)(q0 + lq) * 128;
#pragma unroll
        for (int ks = 0; ks < 4; ks++)
            qf[ks] = *reinterpret_cast<const short8*>(qsrc + ks * 32 + H * 16);
    }

    f32x16 o0, o1;
#pragma unroll
    for (int r = 0; r < 16; r++) { o0[r] = 0.f; o1[r] = 0.f; }
    float m = -1e30f, lsum = 0.f;

    for (int t = 0; t < 16; t++) {
        // ---- stage K tile + V^T tile (8 KB each = 8 gld16 calls each) ----
#pragma unroll
        for (int p = 0; p < 2; p++) {
            const int c = w + p * 4;                 // 0..7
            const int o = c * 1024 + l * 16;         // byte offset in tile
            const int row  = o >> 7;                 // key (K) / d (V^T)
            const int colb = (o & 127) ^ ((l >> 3) << 4);   // pre-swizzled src
            gld16((const char*)Kb + hbytes + (size_t)(t * 64 + row) * 128 + colb,
                  Ks + c * 1024);
            gld16((const char*)Vt + hbytes + (size_t)row * 2048 + t * 128 + colb,
                  Vs + c * 1024);
        }
        __syncthreads();

        // ---- S^T = mfma(K, Q): rows=keys, col=q (=lq) ----
        f32x16 s0, s1;
#pragma unroll
        for (int r = 0; r < 16; r++) { s0[r] = 0.f; s1[r] = 0.f; }
#pragma unroll
        for (int ks = 0; ks < 4; ks++) {
            const int b0 = (lq * 128 + ks * 32 + H * 16) ^ ((lq & 7) << 4);
            short8 k0 = *reinterpret_cast<const short8*>(Ks + b0);
            short8 k1 = *reinterpret_cast<const short8*>(Ks + b0 + 4096);
            s0 = __builtin_amdgcn_mfma_f32_32x32x16_bf16(k0, qf[ks], s0, 0, 0, 0);
            s1 = __builtin_amdgcn_mfma_f32_32x32x16_bf16(k1, qf[ks], s1, 0, 0, 0);
        }

        // ---- online softmax (q = lq; keys split across lane halves) ----
        float tv[32];
#pragma unroll
        for (int r = 0; r < 16; r++) {
            tv[r]      = s0[r] * ATTN_SC;
            tv[16 + r] = s1[r] * ATTN_SC;
        }
        float tmax = tv[0];
#pragma unroll
        for (int r = 1; r < 32; r++) tmax = fmaxf(tmax, tv[r]);
        tmax = fmaxf(tmax, __shfl_xor(tmax, 32));
        const float mnew = fmaxf(m, tmax);
        if (__any(mnew > m)) {
            const float corr = __expf(m - mnew);
            lsum *= corr;
            m = mnew;
#pragma unroll
            for (int r = 0; r < 16; r++) {
                const float cr = __shfl(corr, (r & 3) + 8 * (r >> 2) + 4 * H);
                o0[r] *= cr; o1[r] *= cr;
            }
        }
        float pv[32];
        float ps = 0.f;
#pragma unroll
        for (int r = 0; r < 32; r++) { pv[r] = __expf(tv[r] - m); ps += pv[r]; }
        lsum += ps;

        // ---- P redistribution (pack + half-swap) + PV MFMAs ----
#pragma unroll
        for (int kf = 0; kf < 2; kf++) {
            unsigned c8[8], x8[8];
#pragma unroll
            for (int i = 0; i < 8; i++)
                c8[i] = (unsigned)f2bf_rne(pv[kf * 16 + 2 * i]) |
                        ((unsigned)f2bf_rne(pv[kf * 16 + 2 * i + 1]) << 16);
#pragma unroll
            for (int i = 0; i < 8; i++)
                x8[i] = (unsigned)__shfl_xor((int)c8[i], 32);
#pragma unroll
            for (int tt = 0; tt < 2; tt++) {
                const int b = tt * 4;
                union { unsigned u[4]; short8 v; } pa;
                pa.u[0] = H ? x8[b + 2] : c8[b + 0];
                pa.u[1] = H ? x8[b + 3] : c8[b + 1];
                pa.u[2] = H ? c8[b + 2] : x8[b + 0];
                pa.u[3] = H ? c8[b + 3] : x8[b + 1];
                const int vb0 = (lq * 128 + kf * 64 + tt * 32 + H * 16) ^ ((lq & 7) << 4);
                short8 v0 = *reinterpret_cast<const short8*>(Vs + vb0);
                short8 v1 = *reinterpret_cast<const short8*>(Vs + vb0 + 4096);
                o0 = __builtin_amdgcn_mfma_f32_32x32x16_bf16(pa.v, v0, o0, 0, 0, 0);
                o1 = __builtin_amdgcn_mfma_f32_32x32x16_bf16(pa.v, v1, o1, 0, 0, 0);
            }
        }
        __syncthreads();
    }

    // ---- epilogue: normalize, split hi/lo, store ----
    const float lt = lsum + __shfl_xor(lsum, 32);
#pragma unroll
    for (int r = 0; r < 16; r++) {
        const int qrow = (r & 3) + 8 * (r >> 2) + 4 * H;
        const float inv = 1.f / __shfl(lt, qrow);
        const size_t tok = (size_t)bseg * 1024 + q0 + qrow;
        unsigned short* p0 = ctx + tok * 2048 + h * 64 + lq;
        const float v0f = o0[r] * inv, v1f = o1[r] * inv;
        const unsigned short h0 = f2bf_rne(v0f);
        const unsigned short h1 = f2bf_rne(v1f);
        p0[0]    = h0;
        p0[32]   = h1;
        p0[1024] = f2bf_rne(v0f - bf2f(h0));
        p0[1056] = f2bf_rne(v1f - bf2f(h1));
    }
}

// ---------------------------------------------------------------------------
extern "C" void kernel_launch(void* const* d_in, const int* in_sizes, int n_in,
                              void* d_out, int out_size, void* d_ws, size_t ws_size,
                              hipStream_t stream)
{
    const float* x    = (const float*)d_in[0];
    const float* Wqkv = (const float*)d_in[1];
    const float* bqkv = (const float*)d_in[2];
    const float* Wout = (const float*)d_in[3];
    const float* bout = (const float*)d_in[4];
    float* out = (float*)d_out;

    // workspace layout
    char* ws = (char*)d_ws;
    unsigned short* Ax  = (unsigned short*)(ws);                    // 32 MB
    unsigned short* Wqt = (unsigned short*)(ws + 33554432);         //  6 MB (hi only)
    unsigned short* Wot = (unsigned short*)(ws + 46137344);         //  2 MB (hi only)
    unsigned short* Qb  = (unsigned short*)(ws + 50331648);         // 16 MB
    unsigned short* Kb  = (unsigned short*)(ws + 67108864);         // 16 MB
    unsigned short* Vb  = (unsigned short*)(ws + 83886080);         // 16 MB
    unsigned short* Vt  = (unsigned short*)(ws + 100663296);        // 16 MB
    unsigned short* ctx = (unsigned short*)(ws + 117440512);        // 32 MB

    prep_x_kernel<<<TOKENS, 256, 0, stream>>>(x, Ax);
    prep_w_kernel<<<dim3(96, 32), 256, 0, stream>>>(Wqkv, Wqt, 3072);
    prep_w_kernel<<<dim3(32, 32), 256, 0, stream>>>(Wout, Wot, 1024);

    // QKV projection -> q/k/v bf16 head-major.  grid = (3072/256)*(8192/128)
    //   = 12*64 = 768 blocks (3 exact passes at 1 block/CU), %8 == 0.
    gemm8p_kernel<1><<<768, 512, 0, stream>>>(
        Ax, Wqt, bqkv, (float*)nullptr, Qb, Kb, Vb, 3072, 12);

    vtrans_kernel<<<dim3(128, 16), 256, 0, stream>>>(Vb, Vt);

    attn_mfma_kernel<<<1024, 256, 0, stream>>>(Qb, Kb, Vt, ctx);

    // output projection -> fp32 out.  grid = (1024/256)*(8192/128) = 256 (1 pass)
    gemm8p_kernel<0><<<256, 512, 0, stream>>>(
        ctx, Wot, bout, out, (unsigned short*)nullptr,
        (unsigned short*)nullptr, (unsigned short*)nullptr, 1024, 4);
}